// Round 13
// baseline (1208.985 us; speedup 1.0000x reference)
//
#include <hip/hip_runtime.h>

#define DEV __device__ __forceinline__

typedef __attribute__((ext_vector_type(8))) short bf16x8;
typedef __attribute__((ext_vector_type(4))) float f32x4;
typedef unsigned short u16;
typedef __attribute__((address_space(1))) const void* gvp;
typedef __attribute__((address_space(3))) void* svp;

DEV u16 f2bf(float f){
  unsigned u = __float_as_uint(f);
  u = (u + 0x7FFFu + ((u >> 16) & 1u)) >> 16;
  return (u16)u;
}
DEV float bf2f(u16 v){ return __uint_as_float(((unsigned)v) << 16); }
DEV float2 cmul(float2 a, float2 b){ return make_float2(a.x*b.x - a.y*b.y, a.x*b.y + a.y*b.x); }
DEV int rev8(int i){
  return ((i & 7) << 9) | ((i & 0x38) << 3) | ((i & 0x1C0) >> 3) | ((i >> 9) & 7);
}

// ---------------- fused: LN1 (blocks 0..32767) + weight cvt + bias cat + twiddle ----------------
__global__ __launch_bounds__(256) void k_prepln(const float* __restrict__ x, const float* __restrict__ ln1w,
                       const float* __restrict__ ln1b, u16* __restrict__ Y,
                       const float* __restrict__ Wq, const float* __restrict__ Wk,
                       const float* __restrict__ W1, const float* __restrict__ W2,
                       const float* __restrict__ bq, const float* __restrict__ bk,
                       u16* __restrict__ Wqkb, u16* __restrict__ W1b, u16* __restrict__ W2b,
                       float* __restrict__ bqk, float2* __restrict__ twg){
  const int tid = threadIdx.x;
  if (blockIdx.x < 32768){
    const int row = blockIdx.x;
    const float4 v = ((const float4*)(x + (size_t)row * 1024))[tid];
    float s1 = v.x + v.y + v.z + v.w;
    float s2 = v.x*v.x + v.y*v.y + v.z*v.z + v.w*v.w;
    #pragma unroll
    for (int o = 32; o > 0; o >>= 1){ s1 += __shfl_down(s1, o); s2 += __shfl_down(s2, o); }
    __shared__ float r1[4], r2[4];
    __shared__ float mu_s, rs_s;
    const int wv = tid >> 6;
    if ((tid & 63) == 0){ r1[wv] = s1; r2[wv] = s2; }
    __syncthreads();
    if (tid == 0){
      float t1 = r1[0]+r1[1]+r1[2]+r1[3], t2 = r2[0]+r2[1]+r2[2]+r2[3];
      float mu = t1 * (1.0f/1024.0f);
      float var = t2 * (1.0f/1024.0f) - mu*mu;
      mu_s = mu; rs_s = rsqrtf(var + 1e-6f);
    }
    __syncthreads();
    const float mu = mu_s, rs = rs_s;
    const float4 wv4 = ((const float4*)ln1w)[tid];
    const float4 bv4 = ((const float4*)ln1b)[tid];
    ushort4 o4;
    o4.x = f2bf((v.x-mu)*rs*wv4.x + bv4.x);
    o4.y = f2bf((v.y-mu)*rs*wv4.y + bv4.y);
    o4.z = f2bf((v.z-mu)*rs*wv4.z + bv4.z);
    o4.w = f2bf((v.w-mu)*rs*wv4.w + bv4.w);
    ((ushort4*)(Y + (size_t)row*1024))[tid] = o4;
    return;
  }
  const size_t j = (size_t)(blockIdx.x - 32768) * 256 + tid;
  if (j < 1048576){
    Wqkb[j] = f2bf(Wq[j]);
  } else if (j < 2097152){
    Wqkb[j] = f2bf(Wk[j - 1048576]);
  } else if (j < 6291456){
    W1b[j - 2097152] = f2bf(W1[j - 2097152]);
  } else if (j < 10485760){
    W2b[j - 6291456] = f2bf(W2[j - 6291456]);
  } else if (j < 10487808){
    const int k = (int)(j - 10485760);
    float sn, cs;
    sincosf(-1.5339807878856412e-03f * (float)k, &sn, &cs);
    twg[k] = make_float2(cs, sn);
  } else if (j < 10488832){
    const int k = (int)(j - 10487808);
    bqk[k] = bq[k]; bqk[1024 + k] = bk[k];
  }
}

// ---------------- 256x256 tile, BK=64, 8-phase counted-vmcnt bf16 MFMA GEMM ----------------
// MODE 1: gelu then bf16 store. MODE 2: f32 out[off] += v.
// MODE 3: bf16, transposed feature-major store (out=Qt for gc<1024, out2=Kt else) via LDS restage.
template<int MODE>
__launch_bounds__(512, 2)
__global__ void k_gemm5(const u16* __restrict__ A, const u16* __restrict__ Bw,
                        const float* __restrict__ bias, void* __restrict__ out, void* __restrict__ out2,
                        int M, int N, int K)
{
  __shared__ __align__(16) u16 SMEM[65536];    // 128KB: K-loop dbuf; reused by MODE3 epilogue
  u16 (*LA)[16384] = reinterpret_cast<u16(*)[16384]>(SMEM);
  u16 (*LB)[16384] = reinterpret_cast<u16(*)[16384]>(SMEM + 32768);
  const int tid = threadIdx.x;
  const int wave = tid >> 6, lane = tid & 63;
  const int l15 = lane & 15, l4 = lane >> 4;
  const int wrq = wave >> 2, wcq = wave & 3;   // wave pos inside a 128x128 quadrant
  (void)M;

  // XCD-bijective swizzle (grid % 8 == 0 for all our shapes), bm-major (bn inner)
  const int nwg = gridDim.x;
  const int q8 = nwg >> 3;
  const int wg = (blockIdx.x & 7) * q8 + (blockIdx.x >> 3);
  const int NBN = N >> 8;
  const int bm = wg / NBN, bn = wg % NBN;
  const int NT = K >> 6, NI = NT >> 1;

  // ---- staging geometry: linear LDS dest; inverse-swizzled global source ----
  const int sr8 = lane >> 3;
  const int sch8 = ((lane & 7) ^ (sr8 & 7)) * 8;           // u16 units
  const u16* gA = A  + ((size_t)(bm*256 + wave*16 + sr8)) * K + sch8;
  const u16* gB = Bw + ((size_t)(bn*256 + wave*16 + sr8)) * K + sch8;
  const size_t gH = (size_t)128 * K;                        // +128 rows (half select)
  const size_t gJ = (size_t)8 * K;                          // +8 rows (instr j=1)
  const int lbase = wave * 1024;                            // u16; + half*8192 + j*512

  // ---- asm ds_read bases (byte offsets in LDS); k-XOR baked into second base ----
  const unsigned swzb = (unsigned)((l4 ^ (l15 & 7)) * 16);
  const unsigned uA0  = (unsigned)(uintptr_t)&LA[0][0] + (unsigned)((wrq*64 + l15)*128) + swzb;
  const unsigned uB0  = (unsigned)(uintptr_t)&LB[0][0] + (unsigned)((wcq*32 + l15)*128) + swzb;
  const unsigned uA0x = uA0 ^ 64u, uB0x = uB0 ^ 64u;
  const unsigned uA1  = uA0 + 32768u, uA1x = uA0x + 32768u;
  const unsigned uB1  = uB0 + 32768u, uB1x = uB0x + 32768u;

  f32x4 acc[8][4];
  const f32x4 z4 = {0.f, 0.f, 0.f, 0.f};
  #pragma unroll
  for (int m = 0; m < 8; ++m)
    #pragma unroll
    for (int n = 0; n < 4; ++n) acc[m][n] = z4;

#define DSR(dst, base, OFF) asm volatile("ds_read_b128 %0, %1 offset:" #OFF : "=v"(dst) : "v"(base))

#define LDA_Q0(b0, b1) do{ \
  DSR(fa[0], b0, 0);    DSR(fa[1], b1, 0); \
  DSR(fa[2], b0, 2048); DSR(fa[3], b1, 2048); \
  DSR(fa[4], b0, 4096); DSR(fa[5], b1, 4096); \
  DSR(fa[6], b0, 6144); DSR(fa[7], b1, 6144); }while(0)
#define LDA_Q1(b0, b1) do{ \
  DSR(fa[0], b0, 16384); DSR(fa[1], b1, 16384); \
  DSR(fa[2], b0, 18432); DSR(fa[3], b1, 18432); \
  DSR(fa[4], b0, 20480); DSR(fa[5], b1, 20480); \
  DSR(fa[6], b0, 22528); DSR(fa[7], b1, 22528); }while(0)
#define LDB_Q0(dst, b0, b1) do{ \
  DSR(dst[0], b0, 0);    DSR(dst[1], b1, 0); \
  DSR(dst[2], b0, 2048); DSR(dst[3], b1, 2048); }while(0)
#define LDB_Q1(dst, b0, b1) do{ \
  DSR(dst[0], b0, 16384); DSR(dst[1], b1, 16384); \
  DSR(dst[2], b0, 18432); DSR(dst[3], b1, 18432); }while(0)

#define STG(LD, G, DB, HALF, TK) do{ \
    const int tk_ = (TK) < NT ? (TK) : NT - 1; \
    const u16* g_ = (G) + (size_t)tk_ * 64 + (size_t)(HALF) * gH; \
    u16* l_ = &LD[DB][lbase + (HALF) * 8192]; \
    __builtin_amdgcn_global_load_lds((gvp)g_,        (svp)l_,        16, 0, 0); \
    __builtin_amdgcn_global_load_lds((gvp)(g_ + gJ), (svp)(l_ + 512),16, 0, 0); \
  }while(0)

#define MFMA16(QA, QB, FB) do{ \
    __builtin_amdgcn_s_setprio(1); \
    _Pragma("unroll") for (int kk = 0; kk < 2; ++kk) \
    _Pragma("unroll") for (int mm = 0; mm < 4; ++mm) \
    _Pragma("unroll") for (int nn = 0; nn < 2; ++nn) \
      acc[(QA)*4+mm][(QB)*2+nn] = __builtin_amdgcn_mfma_f32_16x16x32_bf16( \
          fa[mm*2+kk], FB[nn*2+kk], acc[(QA)*4+mm][(QB)*2+nn], 0, 0, 0); \
    __builtin_amdgcn_s_setprio(0); \
  }while(0)

#define SBAR  __builtin_amdgcn_s_barrier()
#define SB0   __builtin_amdgcn_sched_barrier(0)
#define LGKM0 do{ asm volatile("s_waitcnt lgkmcnt(0)" ::: "memory"); SB0; }while(0)
#define LGKM8 asm volatile("s_waitcnt lgkmcnt(8)" ::: "memory")
#define VM4   asm volatile("s_waitcnt vmcnt(4)" ::: "memory")

  // ---- prologue: tile0 (all 4 regions)->db0, A0(1)+B1(1)->db1; confirm tile0 ----
  STG(LA, gA, 0, 0, 0); STG(LA, gA, 0, 1, 0);
  STG(LB, gB, 0, 0, 0); STG(LB, gB, 0, 1, 0);
  STG(LA, gA, 1, 0, 1);
  STG(LB, gB, 1, 1, 1);
  VM4; SBAR;

  for (int it = 0; it < NI; ++it){
    const int u = 2 * it;
    bf16x8 fa[8], fbA[4], fbB[4];
    // ---- tile u in db0 ----
    LDB_Q0(fbA, uB0, uB0x);
    LDA_Q0(uA0, uA0x);
    STG(LA, gA, 1, 1, u+1); STG(LB, gB, 1, 0, u+1);
    LGKM8;
    SBAR; LGKM0; MFMA16(0, 0, fbA); SB0; SBAR;
    LDB_Q1(fbB, uB0, uB0x);
    SBAR; LGKM0; MFMA16(0, 1, fbB); SB0; SBAR;
    LDA_Q1(uA0, uA0x);
    STG(LA, gA, 0, 0, u+2);
    SBAR; LGKM0; MFMA16(1, 1, fbB); SB0; SBAR;
    STG(LB, gB, 0, 1, u+2);
    VM4; SBAR; SB0; MFMA16(1, 0, fbA); SB0; SBAR;
    // ---- tile u+1 in db1 ----
    LDB_Q0(fbA, uB1, uB1x);
    LDA_Q0(uA1, uA1x);
    STG(LA, gA, 0, 1, u+2); STG(LB, gB, 0, 0, u+2);
    LGKM8;
    SBAR; LGKM0; MFMA16(0, 0, fbA); SB0; SBAR;
    LDB_Q1(fbB, uB1, uB1x);
    SBAR; LGKM0; MFMA16(0, 1, fbB); SB0; SBAR;
    LDA_Q1(uA1, uA1x);
    STG(LA, gA, 1, 0, u+3);
    SBAR; LGKM0; MFMA16(1, 1, fbB); SB0; SBAR;
    STG(LB, gB, 1, 1, u+3);
    VM4; SBAR; SB0; MFMA16(1, 0, fbA); SB0; SBAR;
  }
#undef DSR
#undef LDA_Q0
#undef LDA_Q1
#undef LDB_Q0
#undef LDB_Q1
#undef STG
#undef MFMA16
#undef SBAR
#undef SB0
#undef LGKM0
#undef LGKM8
#undef VM4

  if (MODE == 3){
    // drain trailing prefetches, then reuse SMEM as transpose buffer T[128][264]
    asm volatile("s_waitcnt vmcnt(0)" ::: "memory");
    __syncthreads();
    u16* T = SMEM;
    const int bq = bm >> 4;
    const int l0 = (bm & 15) * 256;
    u16* dstb = (u16*)(bn < 4 ? out : out2) + ((size_t)bq*1024 + (bn & 3)*256)*4096 + l0;
    #pragma unroll
    for (int half = 0; half < 2; ++half){
      #pragma unroll
      for (int nn = 0; nn < 2; ++nn){
        const int n = half*2 + nn;
        const int colh = wcq*32 + nn*16 + l15;
        const float bv = bias[bn*256 + half*128 + colh];
        #pragma unroll
        for (int m = 0; m < 8; ++m){
          const int lrow = (m>>2)*128 + wrq*64 + (m&3)*16 + l4*4;
          ushort4 o4;
          o4.x = f2bf(acc[m][n][0] + bv);
          o4.y = f2bf(acc[m][n][1] + bv);
          o4.z = f2bf(acc[m][n][2] + bv);
          o4.w = f2bf(acc[m][n][3] + bv);
          *(ushort4*)&T[colh*264 + lrow] = o4;
        }
      }
      __syncthreads();
      {
        const int c = tid >> 2, lch = (tid & 3) * 64;
        u16* drow = dstb + (size_t)(half*128 + c) * 4096 + lch;
        const u16* srow = &T[c*264 + lch];
        #pragma unroll
        for (int i = 0; i < 8; ++i)
          *(bf16x8*)(drow + i*8) = *(const bf16x8*)(srow + i*8);
      }
      __syncthreads();
    }
  } else {
    #pragma unroll
    for (int m = 0; m < 8; ++m){
      const int gr0 = bm*256 + (m>>2)*128 + wrq*64 + (m&3)*16 + l4*4;
      #pragma unroll
      for (int n = 0; n < 4; ++n){
        const int gc = bn*256 + (n>>1)*128 + wcq*32 + (n&1)*16 + l15;
        const float bv = bias[gc];
        #pragma unroll
        for (int r2 = 0; r2 < 4; ++r2){
          const size_t off = (size_t)(gr0 + r2) * N + gc;
          float v = acc[m][n][r2] + bv;
          if (MODE == 1){
            const float a = 0.7978845608028654f * (v + 0.044715f * v * v * v);
            const float e = __expf(2.0f * a);
            const float th = (e - 1.0f) / (e + 1.0f);
            ((u16*)out)[off] = f2bf(0.5f * v * (1.0f + th));
          } else {
            float* op = (float*)out;
            op[off] += v;
          }
        }
      }
    }
  }
}

// ---------------- radix-8 DIF FFT: natural input -> digit-reversed spectrum (512 threads) ----------------
DEV void fft4096_dif8(float2* Z, const float2* __restrict__ tw, int tid){
  const float C = 0.70710678118654752f;
  #pragma unroll
  for (int s = 4; s >= 1; --s){
    const int q = 1 << (3*(s-1));
    const int step = 1 << (12 - 3*s);
    {
      const int tt = tid;                       // exactly 512 butterflies, 1/thread
      const int j = tt & (q-1);
      const int base = ((tt >> (3*(s-1))) << (3*s)) + j;
      float2 a0 = Z[base],       a1 = Z[base+q],   a2 = Z[base+2*q], a3 = Z[base+3*q];
      float2 a4 = Z[base+4*q],   a5 = Z[base+5*q], a6 = Z[base+6*q], a7 = Z[base+7*q];
      float2 e0 = {a0.x+a4.x, a0.y+a4.y}, o0 = {a0.x-a4.x, a0.y-a4.y};
      float2 e1 = {a2.x+a6.x, a2.y+a6.y}, o1 = {a2.x-a6.x, a2.y-a6.y};
      float2 e2 = {a1.x+a5.x, a1.y+a5.y}, o2 = {a1.x-a5.x, a1.y-a5.y};
      float2 e3 = {a3.x+a7.x, a3.y+a7.y}, o3 = {a3.x-a7.x, a3.y-a7.y};
      float2 E0 = {e0.x+e1.x, e0.y+e1.y}, E1 = {e0.x-e1.x, e0.y-e1.y};
      float2 E2 = {e2.x+e3.x, e2.y+e3.y}, E3 = {e2.x-e3.x, e2.y-e3.y};
      float2 u0 = {E0.x+E2.x, E0.y+E2.y};
      float2 u4 = {E0.x-E2.x, E0.y-E2.y};
      float2 njE3 = {E3.y, -E3.x};
      float2 u2 = {E1.x+njE3.x, E1.y+njE3.y};
      float2 u6 = {E1.x-njE3.x, E1.y-njE3.y};
      float2 W1o2 = {C*(o2.x+o2.y), C*(o2.y-o2.x)};
      float2 W3o2 = {C*(o2.y-o2.x), -C*(o2.x+o2.y)};
      float2 W1o3 = {C*(o3.x+o3.y), C*(o3.y-o3.x)};
      float2 W3o3 = {C*(o3.y-o3.x), -C*(o3.x+o3.y)};
      float2 njo1 = {o1.y, -o1.x};
      float2 u1 = {o0.x + W1o2.x + njo1.x + W3o3.x, o0.y + W1o2.y + njo1.y + W3o3.y};
      float2 u3 = {o0.x + W3o2.x - njo1.x + W1o3.x, o0.y + W3o2.y - njo1.y + W1o3.y};
      float2 u5 = {o0.x - W1o2.x + njo1.x - W3o3.x, o0.y - W1o2.y + njo1.y - W3o3.y};
      float2 u7 = {o0.x - W3o2.x - njo1.x - W1o3.x, o0.y - W3o2.y - njo1.y - W1o3.y};
      const float2 w1 = tw[j*step];
      const float2 w2 = tw[2*j*step];
      const float2 w4 = tw[4*j*step];
      const float2 w3 = cmul(w1, w2);
      const float2 w5 = cmul(w1, w4);
      const float2 w6 = cmul(w2, w4);
      const float2 w7 = cmul(w3, w4);
      Z[base]     = u0;
      Z[base+q]   = cmul(u1, w1);
      Z[base+2*q] = cmul(u2, w2);
      Z[base+3*q] = cmul(u3, w3);
      Z[base+4*q] = cmul(u4, w4);
      Z[base+5*q] = cmul(u5, w5);
      Z[base+6*q] = cmul(u6, w6);
      Z[base+7*q] = cmul(u7, w7);
    }
    __syncthreads();
  }
}

// ---------------- radix-8 DIT inverse FFT: digit-reversed input -> natural output (512 threads) ----------------
DEV void fft4096_dit8_inv(float2* Z, const float2* __restrict__ tw, int tid){
  const float C = 0.70710678118654752f;
  #pragma unroll
  for (int s = 1; s <= 4; ++s){
    const int q = 1 << (3*(s-1));
    const int step = 1 << (12 - 3*s);
    {
      const int tt = tid;
      const int j = tt & (q-1);
      const int base = ((tt >> (3*(s-1))) << (3*s)) + j;
      float2 a0 = Z[base],       a1 = Z[base+q],   a2 = Z[base+2*q], a3 = Z[base+3*q];
      float2 a4 = Z[base+4*q],   a5 = Z[base+5*q], a6 = Z[base+6*q], a7 = Z[base+7*q];
      float2 w1 = tw[j*step];   w1.y = -w1.y;
      float2 w2 = tw[2*j*step]; w2.y = -w2.y;
      float2 w4 = tw[4*j*step]; w4.y = -w4.y;
      const float2 w3 = cmul(w1, w2);
      const float2 w5 = cmul(w1, w4);
      const float2 w6 = cmul(w2, w4);
      const float2 w7 = cmul(w3, w4);
      a1 = cmul(a1, w1); a2 = cmul(a2, w2); a3 = cmul(a3, w3);
      a4 = cmul(a4, w4); a5 = cmul(a5, w5); a6 = cmul(a6, w6); a7 = cmul(a7, w7);
      float2 e0 = {a0.x+a4.x, a0.y+a4.y}, o0 = {a0.x-a4.x, a0.y-a4.y};
      float2 e1 = {a2.x+a6.x, a2.y+a6.y}, o1 = {a2.x-a6.x, a2.y-a6.y};
      float2 e2 = {a1.x+a5.x, a1.y+a5.y}, o2 = {a1.x-a5.x, a1.y-a5.y};
      float2 e3 = {a3.x+a7.x, a3.y+a7.y}, o3 = {a3.x-a7.x, a3.y-a7.y};
      float2 E0 = {e0.x+e1.x, e0.y+e1.y}, E1 = {e0.x-e1.x, e0.y-e1.y};
      float2 E2 = {e2.x+e3.x, e2.y+e3.y}, E3 = {e2.x-e3.x, e2.y-e3.y};
      float2 pjE3 = {-E3.y, E3.x};
      float2 W1o2 = {C*(o2.x-o2.y), C*(o2.x+o2.y)};
      float2 W3o2 = {-C*(o2.x+o2.y), C*(o2.x-o2.y)};
      float2 W1o3 = {C*(o3.x-o3.y), C*(o3.x+o3.y)};
      float2 W3o3 = {-C*(o3.x+o3.y), C*(o3.x-o3.y)};
      float2 pjo1 = {-o1.y, o1.x};
      Z[base]     = make_float2(E0.x+E2.x, E0.y+E2.y);
      Z[base+q]   = make_float2(o0.x + W1o2.x + pjo1.x + W3o3.x, o0.y + W1o2.y + pjo1.y + W3o3.y);
      Z[base+2*q] = make_float2(E1.x+pjE3.x, E1.y+pjE3.y);
      Z[base+3*q] = make_float2(o0.x + W3o2.x - pjo1.x + W1o3.x, o0.y + W3o2.y - pjo1.y + W1o3.y);
      Z[base+4*q] = make_float2(E0.x-E2.x, E0.y-E2.y);
      Z[base+5*q] = make_float2(o0.x - W1o2.x + pjo1.x - W3o3.x, o0.y - W1o2.y + pjo1.y - W3o3.y);
      Z[base+6*q] = make_float2(E1.x-pjE3.x, E1.y-pjE3.y);
      Z[base+7*q] = make_float2(o0.x - W3o2.x - pjo1.x - W1o3.x, o0.y - W3o2.y - pjo1.y - W1o3.y);
    }
    __syncthreads();
  }
}

// ---------------- FFT of (q + i*k) per (b,h,d); write S slice (rev-domain); 512 threads ----------------
__global__ __launch_bounds__(512) void k_fftcorr(const u16* __restrict__ Qt, const u16* __restrict__ Kt,
                                                 const float2* __restrict__ twg, float* __restrict__ S){
  __shared__ float2 Z[4096];      // 32 KB
  const int tid = threadIdx.x;
  const int bh = blockIdx.x, dg = blockIdx.y;
  float2 sa[8];
  #pragma unroll
  for (int j = 0; j < 8; ++j) sa[j] = make_float2(0.f, 0.f);
  for (int dd = 0; dd < 8; ++dd){
    const int d = dg*8 + dd;
    const u16* q  = Qt + ((size_t)bh*64 + d) * 4096;
    const u16* kp = Kt + ((size_t)bh*64 + d) * 4096;
    #pragma unroll
    for (int j = 0; j < 8; ++j){
      const int i = j*512 + tid;
      Z[i] = make_float2(bf2f(q[i]), bf2f(kp[i]));
    }
    __syncthreads();
    fft4096_dif8(Z, twg, tid);
    // position p holds freq f=rev8(p); partner freq (4096-f) at position rev8(4096-f)
    #pragma unroll
    for (int j = 0; j < 8; ++j){
      const int p = j*512 + tid;
      const int f = rev8(p);
      const int p2 = rev8((4096 - f) & 4095);
      const float2 a = Z[p];
      const float2 c = Z[p2];
      const float qr = 0.5f * (a.x + c.x);
      const float qi = 0.5f * (a.y - c.y);
      const float kr = 0.5f * (a.y + c.y);
      const float ki = 0.5f * (c.x - a.x);
      sa[j].x += qr*kr + qi*ki;     // Re(qf * conj(kf))
      sa[j].y += qi*kr - qr*ki;     // Im(qf * conj(kf))
    }
    __syncthreads();
  }
  float2* Sg = (float2*)S + ((size_t)dg*128 + bh) * 4096;
  #pragma unroll
  for (int j = 0; j < 8; ++j)
    Sg[j*512 + tid] = sa[j];
}

// ---------------- sum 8 S slices; inverse DIT FFT -> corr; softmax over L -> attn; 512 threads ----------------
__global__ __launch_bounds__(512) void k_isoftmax(const float* __restrict__ S, const float2* __restrict__ twg,
                                                  float* __restrict__ attn){
  __shared__ float2 Z[4096];
  __shared__ float red[8];
  __shared__ float bc;
  const int tid = threadIdx.x;
  const int bh = blockIdx.x;
  const float2* S2 = (const float2*)S;
  #pragma unroll
  for (int j = 0; j < 8; ++j){
    const int i = j*512 + tid;
    float2 acc = make_float2(0.f, 0.f);
    #pragma unroll
    for (int g = 0; g < 8; ++g){
      const float2 v = S2[((size_t)g*128 + bh) * 4096 + i];
      acc.x += v.x; acc.y += v.y;
    }
    Z[i] = acc;
  }
  __syncthreads();
  fft4096_dit8_inv(Z, twg, tid);      // rev-domain in -> natural out (unnormalized)
  const float scale = 1.0f / (4096.0f * 64.0f);   // 1/N (ifft) * 1/HD (mean over d)
  float cr[8];
  float lmax = -1e30f;
  #pragma unroll
  for (int j = 0; j < 8; ++j){
    const float c = Z[j*512 + tid].x * scale;
    cr[j] = c;
    lmax = fmaxf(lmax, c);
  }
  #pragma unroll
  for (int o = 32; o > 0; o >>= 1) lmax = fmaxf(lmax, __shfl_down(lmax, o));
  if ((tid & 63) == 0) red[tid >> 6] = lmax;
  __syncthreads();
  if (tid == 0){
    float m = red[0];
    #pragma unroll
    for (int k = 1; k < 8; ++k) m = fmaxf(m, red[k]);
    bc = m;
  }
  __syncthreads();
  const float gmax = bc;
  float lsum = 0.f;
  #pragma unroll
  for (int j = 0; j < 8; ++j){ cr[j] = __expf(cr[j] - gmax); lsum += cr[j]; }
  #pragma unroll
  for (int o = 32; o > 0; o >>= 1) lsum += __shfl_down(lsum, o);
  if ((tid & 63) == 0) red[tid >> 6] = lsum;
  __syncthreads();
  if (tid == 0){
    float s = 0.f;
    #pragma unroll
    for (int k = 0; k < 8; ++k) s += red[k];
    bc = s;
  }
  __syncthreads();
  const float inv = 1.0f / bc;
  float* at = attn + (size_t)bh * 4096;
  #pragma unroll
  for (int j = 0; j < 8; ++j) at[j*512 + tid] = cr[j] * inv;
}

// ---------------- yws[b][lq][h][:] = sum_{l in chunk} attn[b,h,l] * y[b,l,:]  (slice, no atomics) ----------------
__global__ __launch_bounds__(256) void k_yw(const float* __restrict__ attn, const u16* __restrict__ Y,
                                            float* __restrict__ yws){
  __shared__ float at[128*20 + 4];
  const int b = blockIdx.x, lq = blockIdx.y;
  const int l0 = lq * 128;
  const int tid = threadIdx.x;
  for (int idx = tid; idx < 2048; idx += 256){
    const int h = idx >> 7, l = idx & 127;
    at[l*20 + h] = attn[((size_t)b*16 + h)*4096 + l0 + l];
  }
  __syncthreads();
  float acc[16][4];
  #pragma unroll
  for (int h = 0; h < 16; ++h)
    #pragma unroll
    for (int j = 0; j < 4; ++j) acc[h][j] = 0.f;
  const u16* yb = Y + ((size_t)b*4096 + l0)*1024 + tid*4;
  for (int l = 0; l < 128; ++l){
    const ushort4 yv4 = *(const ushort4*)(yb + (size_t)l*1024);
    const float y0 = bf2f(yv4.x), y1 = bf2f(yv4.y), y2 = bf2f(yv4.z), y3 = bf2f(yv4.w);
    #pragma unroll
    for (int hq = 0; hq < 4; ++hq){
      const float4 a4 = *(const float4*)&at[l*20 + hq*4];
      acc[hq*4+0][0] += a4.x*y0; acc[hq*4+0][1] += a4.x*y1; acc[hq*4+0][2] += a4.x*y2; acc[hq*4+0][3] += a4.x*y3;
      acc[hq*4+1][0] += a4.y*y0; acc[hq*4+1][1] += a4.y*y1; acc[hq*4+1][2] += a4.y*y2; acc[hq*4+1][3] += a4.y*y3;
      acc[hq*4+2][0] += a4.z*y0; acc[hq*4+2][1] += a4.z*y1; acc[hq*4+2][2] += a4.z*y2; acc[hq*4+2][3] += a4.z*y3;
      acc[hq*4+3][0] += a4.w*y0; acc[hq*4+3][1] += a4.w*y1; acc[hq*4+3][2] += a4.w*y2; acc[hq*4+3][3] += a4.w*y3;
    }
  }
  float* ywb = yws + ((size_t)(b*32 + lq)*16) * 1024 + tid*4;
  #pragma unroll
  for (int h = 0; h < 16; ++h)
    #pragma unroll
    for (int j = 0; j < 4; ++j)
      ywb[(size_t)h*1024 + j] = acc[h][j];
}

// ---------------- oav[b, hd*16+h] = bv[h*64+hd] + (sum_lq yws[b][lq][h,:]) . Wv[h*64+hd,:] ----------------
__global__ __launch_bounds__(256) void k_vproj(const float* __restrict__ yws, const float* __restrict__ Wv,
                                               const float* __restrict__ bv, float* __restrict__ oav){
  __shared__ float yv[1024];
  const int b = blockIdx.x, h = blockIdx.y;
  const int tid = threadIdx.x;
  for (int i = tid; i < 1024; i += 256){
    float a = 0.f;
    #pragma unroll 8
    for (int g = 0; g < 32; ++g)
      a += yws[((size_t)(b*32 + g)*16 + h)*1024 + i];
    yv[i] = a;
  }
  __syncthreads();
  const int hd = tid >> 2, q = tid & 3;
  const float4* wr = (const float4*)(Wv + (size_t)(h*64 + hd)*1024 + q*256);
  float acc = 0.f;
  #pragma unroll 4
  for (int i = 0; i < 64; ++i){
    const float4 w4 = wr[i];
    acc += yv[q*256+4*i]*w4.x + yv[q*256+4*i+1]*w4.y + yv[q*256+4*i+2]*w4.z + yv[q*256+4*i+3]*w4.w;
  }
  acc += __shfl_xor(acc, 1);
  acc += __shfl_xor(acc, 2);
  if (q == 0) oav[(size_t)b*1024 + hd*16 + h] = acc + bv[h*64 + hd];
}

// ---------------- proj = oav @ Wo^T + bo  (8 x 1024) ----------------
__global__ __launch_bounds__(256) void k_proj(const float* __restrict__ oav, const float* __restrict__ Wo,
                                              const float* __restrict__ bo, float* __restrict__ proj){
  const int b = blockIdx.x;
  const int o = blockIdx.y * 256 + threadIdx.x;
  __shared__ float xin[1024];
  for (int i = threadIdx.x; i < 1024; i += 256) xin[i] = oav[(size_t)b*1024 + i];
  __syncthreads();
  float acc = bo[o];
  const float4* wr = (const float4*)(Wo + (size_t)o * 1024);
  #pragma unroll 4
  for (int i = 0; i < 256; ++i){
    const float4 w4 = wr[i];
    acc += xin[4*i]*w4.x + xin[4*i+1]*w4.y + xin[4*i+2]*w4.z + xin[4*i+3]*w4.w;
  }
  proj[(size_t)b*1024 + o] = acc;
}

// ---------------- fused decomp+LN2, barrier-free: wave owns one l-row, lane owns 16 d ----------------
// grid (8 b, 64 lc), 512 threads = 8 waves; wave w handles l = lc*64 + w*8 .. +7.
__global__ __launch_bounds__(512) void k_decln(const float* __restrict__ x, const float* __restrict__ proj,
                                               const float* __restrict__ w, const float* __restrict__ bvec,
                                               float* __restrict__ out, u16* __restrict__ y){
  const int b = blockIdx.x, lc = blockIdx.y;
  const int wave = threadIdx.x >> 6, lane = threadIdx.x & 63;
  const int l0 = lc*64 + wave*8;
  const int d0 = lane * 16;
  const float* xb = x + (size_t)b*4096*1024 + d0;
  float* ob = out + (size_t)b*4096*1024 + d0;
  u16* yb = y + (size_t)b*4096*1024 + d0;
  float pv[16], wv[16], bv[16], wsum[16];
  #pragma unroll
  for (int k = 0; k < 4; ++k){
    const float4 p4 = *(const float4*)(proj + (size_t)b*1024 + d0 + k*4);
    const float4 w4 = *(const float4*)(w + d0 + k*4);
    const float4 b4 = *(const float4*)(bvec + d0 + k*4);
    pv[k*4+0]=p4.x; pv[k*4+1]=p4.y; pv[k*4+2]=p4.z; pv[k*4+3]=p4.w;
    wv[k*4+0]=w4.x; wv[k*4+1]=w4.y; wv[k*4+2]=w4.z; wv[k*4+3]=w4.w;
    bv[k*4+0]=b4.x; bv[k*4+1]=b4.y; bv[k*4+2]=b4.z; bv[k*4+3]=b4.w;
    wsum[k*4+0]=0.f; wsum[k*4+1]=0.f; wsum[k*4+2]=0.f; wsum[k*4+3]=0.f;
  }
  float cnt = 0.f;
  const int lo = (l0 - 12 < 0) ? 0 : l0 - 12;
  const int hi = (l0 + 11 > 4095) ? 4095 : l0 + 11;
  for (int ll = lo; ll <= hi; ++ll){
    #pragma unroll
    for (int k = 0; k < 4; ++k){
      const float4 v = *(const float4*)(xb + (size_t)ll*1024 + k*4);
      wsum[k*4+0]+=v.x; wsum[k*4+1]+=v.y; wsum[k*4+2]+=v.z; wsum[k*4+3]+=v.w;
    }
    cnt += 1.f;
  }
  for (int l = l0; l < l0 + 8; ++l){
    if (l + 12 < 4096){
      #pragma unroll
      for (int k = 0; k < 4; ++k){
        const float4 v = *(const float4*)(xb + (size_t)(l+12)*1024 + k*4);
        wsum[k*4+0]+=v.x; wsum[k*4+1]+=v.y; wsum[k*4+2]+=v.z; wsum[k*4+3]+=v.w;
      }
      cnt += 1.f;
    }
    float x2[16];
    float s1 = 0.f, s2 = 0.f;
    #pragma unroll
    for (int k = 0; k < 4; ++k){
      const float4 v = *(const float4*)(xb + (size_t)l*1024 + k*4);
      const float xc[4] = {v.x, v.y, v.z, v.w};
      #pragma unroll
      for (int j = 0; j < 4; ++j){
        const int idx = k*4 + j;
        x2[idx] = xc[j] + pv[idx] - (wsum[idx] + cnt*pv[idx]) * 0.04f;
        s1 += x2[idx]; s2 += x2[idx]*x2[idx];
      }
      float4 o4 = {x2[k*4+0], x2[k*4+1], x2[k*4+2], x2[k*4+3]};
      *(float4*)(ob + (size_t)l*1024 + k*4) = o4;
    }
    #pragma unroll
    for (int o = 32; o > 0; o >>= 1){ s1 += __shfl_xor(s1, o); s2 += __shfl_xor(s2, o); }
    const float mu = s1 * (1.0f/1024.0f);
    const float rs = rsqrtf(s2*(1.0f/1024.0f) - mu*mu + 1e-6f);
    #pragma unroll
    for (int k = 0; k < 4; ++k){
      ushort4 y4;
      y4.x = f2bf((x2[k*4+0]-mu)*rs*wv[k*4+0] + bv[k*4+0]);
      y4.y = f2bf((x2[k*4+1]-mu)*rs*wv[k*4+1] + bv[k*4+1]);
      y4.z = f2bf((x2[k*4+2]-mu)*rs*wv[k*4+2] + bv[k*4+2]);
      y4.w = f2bf((x2[k*4+3]-mu)*rs*wv[k*4+3] + bv[k*4+3]);
      *(ushort4*)(yb + (size_t)l*1024 + k*4) = y4;
    }
    if (l >= 12){
      #pragma unroll
      for (int k = 0; k < 4; ++k){
        const float4 v = *(const float4*)(xb + (size_t)(l-12)*1024 + k*4);
        wsum[k*4+0]-=v.x; wsum[k*4+1]-=v.y; wsum[k*4+2]-=v.z; wsum[k*4+3]-=v.w;
      }
      cnt -= 1.f;
    }
  }
}

extern "C" void kernel_launch(void* const* d_in, const int* in_sizes, int n_in,
                              void* d_out, int out_size, void* d_ws, size_t ws_size,
                              hipStream_t stream){
  const float* x    = (const float*)d_in[0];
  const float* ln1w = (const float*)d_in[1];
  const float* ln1b = (const float*)d_in[2];
  const float* Wq   = (const float*)d_in[3];
  const float* bq   = (const float*)d_in[4];
  const float* Wk   = (const float*)d_in[5];
  const float* bk   = (const float*)d_in[6];
  const float* Wv   = (const float*)d_in[7];
  const float* bv   = (const float*)d_in[8];
  const float* Wo   = (const float*)d_in[9];
  const float* bo   = (const float*)d_in[10];
  const float* ln2w = (const float*)d_in[11];
  const float* ln2b = (const float*)d_in[12];
  const float* W1   = (const float*)d_in[13];
  const float* b1   = (const float*)d_in[14];
  const float* W2   = (const float*)d_in[15];
  const float* b2   = (const float*)d_in[16];
  float* out = (float*)d_out;

  char* ws = (char*)d_ws;
  // [0,32MB): S slices (fftcorr->isoftmax), then yws slices (yw->vproj), then H1 (MLP).
  float* S    = (float*)(ws + 0);             // 8 x 128 x 8192 f32 = 32MB
  float* yws  = (float*)(ws + 0);             // 8 x 32 x 16 x 1024 f32 = 16MB (after isoftmax)
  u16* Qt   = (u16*)(ws + 134217728);         // 64MB (B,H,64,L) bf16
  u16* Kt   = (u16*)(ws + 201326592);         // 64MB
  u16* H1   = (u16*)(ws + 0);                 // 256MB late (after vproj done with yws)
  u16* Y    = (u16*)(ws + 268435456);         // 64MB; ln1 y, later ln2 y
  float2* twg = (float2*)(ws + 339738624);    // 16 KB
  float* attn = (float*)(ws + 339755008);     // 2 MB
  float* oav  = (float*)(ws + 342376448);     // 32 KB
  float* proj = (float*)(ws + 342409216);     // 32 KB
  float* bqk  = (float*)(ws + 342441984);     // 8 KB
  u16* Wqkb   = (u16*)(ws + 342450176);       // 4 MB
  u16* W1b    = (u16*)(ws + 346644480);       // 8 MB
  u16* W2b    = (u16*)(ws + 355033088);       // 8 MB

  // fused LN1 + weight cvt + bias cat + twiddle (single launch; LN blocks first)
  k_prepln<<<73740, 256, 0, stream>>>(x, ln1w, ln1b, Y, Wq, Wk, W1, W2, bq, bk,
                                      Wqkb, W1b, W2b, bqk, twg);

  // fused QK projection with transposed store straight into Qt/Kt (MODE 3)
  k_gemm5<3><<<1024, 512, 0, stream>>>(Y, Wqkb, bqk, Qt, Kt, 32768, 2048, 1024);

  // S slices (rev-domain) = per-dg sum_d rfft(Q_d) * conj(rfft(K_d)); no atomics; 512-thr FFT
  k_fftcorr<<<dim3(128, 8), 512, 0, stream>>>(Qt, Kt, twg, S);
  // corr = ifft(sum_g S_g)/(N*HD); attn = softmax(corr); 512-thr FFT
  k_isoftmax<<<128, 512, 0, stream>>>(S, twg, attn);

  // yws slices = per-lq sum_l attn*y;  oav = (sum yws) @ Wv^T + bv;  proj = oav @ Wo^T + bo
  k_yw<<<dim3(8, 32), 256, 0, stream>>>(attn, Y, yws);
  k_vproj<<<dim3(8, 16), 256, 0, stream>>>(yws, Wv, bv, oav);
  k_proj<<<dim3(8, 4), 256, 0, stream>>>(oav, Wo, bo, proj);

  // fused: x2 = (x + proj) - movavg25(x + proj) -> d_out;  Y = LN2(x2)   (barrier-free)
  k_decln<<<dim3(8, 64), 512, 0, stream>>>(x, proj, ln2w, ln2b, out, Y);

  // MLP
  k_gemm5<1><<<2048, 512, 0, stream>>>(Y, W1b, b1, H1, nullptr, 32768, 4096, 1024);
  k_gemm5<2><<<512, 512, 0, stream>>>(H1, W2b, b2, out, nullptr, 32768, 1024, 4096);
}

// Round 14
// 1202.732 us; speedup vs baseline: 1.0052x; 1.0052x over previous
//
#include <hip/hip_runtime.h>

#define DEV __device__ __forceinline__

typedef __attribute__((ext_vector_type(8))) short bf16x8;
typedef __attribute__((ext_vector_type(4))) float f32x4;
typedef unsigned short u16;
typedef __attribute__((address_space(1))) const void* gvp;
typedef __attribute__((address_space(3))) void* svp;

DEV u16 f2bf(float f){
  unsigned u = __float_as_uint(f);
  u = (u + 0x7FFFu + ((u >> 16) & 1u)) >> 16;
  return (u16)u;
}
DEV float bf2f(u16 v){ return __uint_as_float(((unsigned)v) << 16); }
DEV float2 cmul(float2 a, float2 b){ return make_float2(a.x*b.x - a.y*b.y, a.x*b.y + a.y*b.x); }
DEV int rev8(int i){
  return ((i & 7) << 9) | ((i & 0x38) << 3) | ((i & 0x1C0) >> 3) | ((i >> 9) & 7);
}

// ---------------- fused: LN1 (blocks 0..32767) + weight cvt + bias cat + twiddle ----------------
__global__ __launch_bounds__(256) void k_prepln(const float* __restrict__ x, const float* __restrict__ ln1w,
                       const float* __restrict__ ln1b, u16* __restrict__ Y,
                       const float* __restrict__ Wq, const float* __restrict__ Wk,
                       const float* __restrict__ W1, const float* __restrict__ W2,
                       const float* __restrict__ bq, const float* __restrict__ bk,
                       u16* __restrict__ Wqkb, u16* __restrict__ W1b, u16* __restrict__ W2b,
                       float* __restrict__ bqk, float2* __restrict__ twg){
  const int tid = threadIdx.x;
  if (blockIdx.x < 32768){
    const int row = blockIdx.x;
    const float4 v = ((const float4*)(x + (size_t)row * 1024))[tid];
    float s1 = v.x + v.y + v.z + v.w;
    float s2 = v.x*v.x + v.y*v.y + v.z*v.z + v.w*v.w;
    #pragma unroll
    for (int o = 32; o > 0; o >>= 1){ s1 += __shfl_down(s1, o); s2 += __shfl_down(s2, o); }
    __shared__ float r1[4], r2[4];
    __shared__ float mu_s, rs_s;
    const int wv = tid >> 6;
    if ((tid & 63) == 0){ r1[wv] = s1; r2[wv] = s2; }
    __syncthreads();
    if (tid == 0){
      float t1 = r1[0]+r1[1]+r1[2]+r1[3], t2 = r2[0]+r2[1]+r2[2]+r2[3];
      float mu = t1 * (1.0f/1024.0f);
      float var = t2 * (1.0f/1024.0f) - mu*mu;
      mu_s = mu; rs_s = rsqrtf(var + 1e-6f);
    }
    __syncthreads();
    const float mu = mu_s, rs = rs_s;
    const float4 wv4 = ((const float4*)ln1w)[tid];
    const float4 bv4 = ((const float4*)ln1b)[tid];
    ushort4 o4;
    o4.x = f2bf((v.x-mu)*rs*wv4.x + bv4.x);
    o4.y = f2bf((v.y-mu)*rs*wv4.y + bv4.y);
    o4.z = f2bf((v.z-mu)*rs*wv4.z + bv4.z);
    o4.w = f2bf((v.w-mu)*rs*wv4.w + bv4.w);
    ((ushort4*)(Y + (size_t)row*1024))[tid] = o4;
    return;
  }
  const size_t j = (size_t)(blockIdx.x - 32768) * 256 + tid;
  if (j < 1048576){
    Wqkb[j] = f2bf(Wq[j]);
  } else if (j < 2097152){
    Wqkb[j] = f2bf(Wk[j - 1048576]);
  } else if (j < 6291456){
    W1b[j - 2097152] = f2bf(W1[j - 2097152]);
  } else if (j < 10485760){
    W2b[j - 6291456] = f2bf(W2[j - 6291456]);
  } else if (j < 10487808){
    const int k = (int)(j - 10485760);
    float sn, cs;
    sincosf(-1.5339807878856412e-03f * (float)k, &sn, &cs);
    twg[k] = make_float2(cs, sn);
  } else if (j < 10488832){
    const int k = (int)(j - 10487808);
    bqk[k] = bq[k]; bqk[1024 + k] = bk[k];
  }
}

// ---------------- 256x256 tile, BK=64, 8-phase counted-vmcnt bf16 MFMA GEMM ----------------
// MODE 1: gelu then bf16 store. MODE 2: f32 out[off] += v.
// MODE 3: bf16, transposed feature-major store (out=Qt for gc<1024, out2=Kt else) via LDS restage.
// R14: minimal sched_barrier pins (only the rule-#18-required SB0 after lgkmcnt(0)).
template<int MODE>
__launch_bounds__(512, 2)
__global__ void k_gemm5(const u16* __restrict__ A, const u16* __restrict__ Bw,
                        const float* __restrict__ bias, void* __restrict__ out, void* __restrict__ out2,
                        int M, int N, int K)
{
  __shared__ __align__(16) u16 SMEM[65536];    // 128KB: K-loop dbuf; reused by MODE3 epilogue
  u16 (*LA)[16384] = reinterpret_cast<u16(*)[16384]>(SMEM);
  u16 (*LB)[16384] = reinterpret_cast<u16(*)[16384]>(SMEM + 32768);
  const int tid = threadIdx.x;
  const int wave = tid >> 6, lane = tid & 63;
  const int l15 = lane & 15, l4 = lane >> 4;
  const int wrq = wave >> 2, wcq = wave & 3;   // wave pos inside a 128x128 quadrant
  (void)M;

  // XCD-bijective swizzle (grid % 8 == 0 for all our shapes), bm-major (bn inner)
  const int nwg = gridDim.x;
  const int q8 = nwg >> 3;
  const int wg = (blockIdx.x & 7) * q8 + (blockIdx.x >> 3);
  const int NBN = N >> 8;
  const int bm = wg / NBN, bn = wg % NBN;
  const int NT = K >> 6, NI = NT >> 1;

  // ---- staging geometry: linear LDS dest; inverse-swizzled global source ----
  const int sr8 = lane >> 3;
  const int sch8 = ((lane & 7) ^ (sr8 & 7)) * 8;           // u16 units
  const u16* gA = A  + ((size_t)(bm*256 + wave*16 + sr8)) * K + sch8;
  const u16* gB = Bw + ((size_t)(bn*256 + wave*16 + sr8)) * K + sch8;
  const size_t gH = (size_t)128 * K;                        // +128 rows (half select)
  const size_t gJ = (size_t)8 * K;                          // +8 rows (instr j=1)
  const int lbase = wave * 1024;                            // u16; + half*8192 + j*512

  // ---- asm ds_read bases (byte offsets in LDS); k-XOR baked into second base ----
  const unsigned swzb = (unsigned)((l4 ^ (l15 & 7)) * 16);
  const unsigned uA0  = (unsigned)(uintptr_t)&LA[0][0] + (unsigned)((wrq*64 + l15)*128) + swzb;
  const unsigned uB0  = (unsigned)(uintptr_t)&LB[0][0] + (unsigned)((wcq*32 + l15)*128) + swzb;
  const unsigned uA0x = uA0 ^ 64u, uB0x = uB0 ^ 64u;
  const unsigned uA1  = uA0 + 32768u, uA1x = uA0x + 32768u;
  const unsigned uB1  = uB0 + 32768u, uB1x = uB0x + 32768u;

  f32x4 acc[8][4];
  const f32x4 z4 = {0.f, 0.f, 0.f, 0.f};
  #pragma unroll
  for (int m = 0; m < 8; ++m)
    #pragma unroll
    for (int n = 0; n < 4; ++n) acc[m][n] = z4;

#define DSR(dst, base, OFF) asm volatile("ds_read_b128 %0, %1 offset:" #OFF : "=v"(dst) : "v"(base))

#define LDA_Q0(b0, b1) do{ \
  DSR(fa[0], b0, 0);    DSR(fa[1], b1, 0); \
  DSR(fa[2], b0, 2048); DSR(fa[3], b1, 2048); \
  DSR(fa[4], b0, 4096); DSR(fa[5], b1, 4096); \
  DSR(fa[6], b0, 6144); DSR(fa[7], b1, 6144); }while(0)
#define LDA_Q1(b0, b1) do{ \
  DSR(fa[0], b0, 16384); DSR(fa[1], b1, 16384); \
  DSR(fa[2], b0, 18432); DSR(fa[3], b1, 18432); \
  DSR(fa[4], b0, 20480); DSR(fa[5], b1, 20480); \
  DSR(fa[6], b0, 22528); DSR(fa[7], b1, 22528); }while(0)
#define LDB_Q0(dst, b0, b1) do{ \
  DSR(dst[0], b0, 0);    DSR(dst[1], b1, 0); \
  DSR(dst[2], b0, 2048); DSR(dst[3], b1, 2048); }while(0)
#define LDB_Q1(dst, b0, b1) do{ \
  DSR(dst[0], b0, 16384); DSR(dst[1], b1, 16384); \
  DSR(dst[2], b0, 18432); DSR(dst[3], b1, 18432); }while(0)

#define STG(LD, G, DB, HALF, TK) do{ \
    const int tk_ = (TK) < NT ? (TK) : NT - 1; \
    const u16* g_ = (G) + (size_t)tk_ * 64 + (size_t)(HALF) * gH; \
    u16* l_ = &LD[DB][lbase + (HALF) * 8192]; \
    __builtin_amdgcn_global_load_lds((gvp)g_,        (svp)l_,        16, 0, 0); \
    __builtin_amdgcn_global_load_lds((gvp)(g_ + gJ), (svp)(l_ + 512),16, 0, 0); \
  }while(0)

#define MFMA16(QA, QB, FB) do{ \
    __builtin_amdgcn_s_setprio(1); \
    _Pragma("unroll") for (int kk = 0; kk < 2; ++kk) \
    _Pragma("unroll") for (int mm = 0; mm < 4; ++mm) \
    _Pragma("unroll") for (int nn = 0; nn < 2; ++nn) \
      acc[(QA)*4+mm][(QB)*2+nn] = __builtin_amdgcn_mfma_f32_16x16x32_bf16( \
          fa[mm*2+kk], FB[nn*2+kk], acc[(QA)*4+mm][(QB)*2+nn], 0, 0, 0); \
    __builtin_amdgcn_s_setprio(0); \
  }while(0)

#define SBAR  __builtin_amdgcn_s_barrier()
#define SB0   __builtin_amdgcn_sched_barrier(0)
#define LGKM0 do{ asm volatile("s_waitcnt lgkmcnt(0)" ::: "memory"); SB0; }while(0)
#define LGKM8 asm volatile("s_waitcnt lgkmcnt(8)" ::: "memory")
#define VM4   asm volatile("s_waitcnt vmcnt(4)" ::: "memory")

  // ---- prologue: tile0 (all 4 regions)->db0, A0(1)+B1(1)->db1; confirm tile0 ----
  STG(LA, gA, 0, 0, 0); STG(LA, gA, 0, 1, 0);
  STG(LB, gB, 0, 0, 0); STG(LB, gB, 0, 1, 0);
  STG(LA, gA, 1, 0, 1);
  STG(LB, gB, 1, 1, 1);
  VM4; SBAR;

  for (int it = 0; it < NI; ++it){
    const int u = 2 * it;
    bf16x8 fa[8], fbA[4], fbB[4];
    // ---- tile u in db0 ----
    LDB_Q0(fbA, uB0, uB0x);
    LDA_Q0(uA0, uA0x);
    STG(LA, gA, 1, 1, u+1); STG(LB, gB, 1, 0, u+1);
    LGKM8;
    SBAR; LGKM0; MFMA16(0, 0, fbA); SBAR;
    LDB_Q1(fbB, uB0, uB0x);
    SBAR; LGKM0; MFMA16(0, 1, fbB); SBAR;
    LDA_Q1(uA0, uA0x);
    STG(LA, gA, 0, 0, u+2);
    SBAR; LGKM0; MFMA16(1, 1, fbB); SBAR;
    STG(LB, gB, 0, 1, u+2);
    VM4; SBAR; MFMA16(1, 0, fbA); SBAR;
    // ---- tile u+1 in db1 ----
    LDB_Q0(fbA, uB1, uB1x);
    LDA_Q0(uA1, uA1x);
    STG(LA, gA, 0, 1, u+2); STG(LB, gB, 0, 0, u+2);
    LGKM8;
    SBAR; LGKM0; MFMA16(0, 0, fbA); SBAR;
    LDB_Q1(fbB, uB1, uB1x);
    SBAR; LGKM0; MFMA16(0, 1, fbB); SBAR;
    LDA_Q1(uA1, uA1x);
    STG(LA, gA, 1, 0, u+3);
    SBAR; LGKM0; MFMA16(1, 1, fbB); SBAR;
    STG(LB, gB, 1, 1, u+3);
    VM4; SBAR; MFMA16(1, 0, fbA); SBAR;
  }
#undef DSR
#undef LDA_Q0
#undef LDA_Q1
#undef LDB_Q0
#undef LDB_Q1
#undef STG
#undef MFMA16
#undef SBAR
#undef SB0
#undef LGKM0
#undef LGKM8
#undef VM4

  if (MODE == 3){
    // drain trailing prefetches, then reuse SMEM as transpose buffer T[128][264]
    asm volatile("s_waitcnt vmcnt(0)" ::: "memory");
    __syncthreads();
    u16* T = SMEM;
    const int bq = bm >> 4;
    const int l0 = (bm & 15) * 256;
    u16* dstb = (u16*)(bn < 4 ? out : out2) + ((size_t)bq*1024 + (bn & 3)*256)*4096 + l0;
    #pragma unroll
    for (int half = 0; half < 2; ++half){
      #pragma unroll
      for (int nn = 0; nn < 2; ++nn){
        const int n = half*2 + nn;
        const int colh = wcq*32 + nn*16 + l15;
        const float bv = bias[bn*256 + half*128 + colh];
        #pragma unroll
        for (int m = 0; m < 8; ++m){
          const int lrow = (m>>2)*128 + wrq*64 + (m&3)*16 + l4*4;
          ushort4 o4;
          o4.x = f2bf(acc[m][n][0] + bv);
          o4.y = f2bf(acc[m][n][1] + bv);
          o4.z = f2bf(acc[m][n][2] + bv);
          o4.w = f2bf(acc[m][n][3] + bv);
          *(ushort4*)&T[colh*264 + lrow] = o4;
        }
      }
      __syncthreads();
      {
        const int c = tid >> 2, lch = (tid & 3) * 64;
        u16* drow = dstb + (size_t)(half*128 + c) * 4096 + lch;
        const u16* srow = &T[c*264 + lch];
        #pragma unroll
        for (int i = 0; i < 8; ++i)
          *(bf16x8*)(drow + i*8) = *(const bf16x8*)(srow + i*8);
      }
      __syncthreads();
    }
  } else {
    #pragma unroll
    for (int m = 0; m < 8; ++m){
      const int gr0 = bm*256 + (m>>2)*128 + wrq*64 + (m&3)*16 + l4*4;
      #pragma unroll
      for (int n = 0; n < 4; ++n){
        const int gc = bn*256 + (n>>1)*128 + wcq*32 + (n&1)*16 + l15;
        const float bv = bias[gc];
        #pragma unroll
        for (int r2 = 0; r2 < 4; ++r2){
          const size_t off = (size_t)(gr0 + r2) * N + gc;
          float v = acc[m][n][r2] + bv;
          if (MODE == 1){
            const float a = 0.7978845608028654f * (v + 0.044715f * v * v * v);
            const float e = __expf(2.0f * a);
            const float th = (e - 1.0f) / (e + 1.0f);
            ((u16*)out)[off] = f2bf(0.5f * v * (1.0f + th));
          } else {
            float* op = (float*)out;
            op[off] += v;
          }
        }
      }
    }
  }
}

// ---------------- radix-8 DIF FFT: natural input -> octal-digit-reversed spectrum ----------------
DEV void fft4096_dif8(float2* Z, const float2* __restrict__ tw, int tid){
  const float C = 0.70710678118654752f;
  #pragma unroll
  for (int s = 4; s >= 1; --s){
    const int q = 1 << (3*(s-1));
    const int step = 1 << (12 - 3*s);
    #pragma unroll
    for (int tt = tid; tt < 512; tt += 256){
      const int j = tt & (q-1);
      const int base = ((tt >> (3*(s-1))) << (3*s)) + j;
      float2 a0 = Z[base],       a1 = Z[base+q],   a2 = Z[base+2*q], a3 = Z[base+3*q];
      float2 a4 = Z[base+4*q],   a5 = Z[base+5*q], a6 = Z[base+6*q], a7 = Z[base+7*q];
      float2 e0 = {a0.x+a4.x, a0.y+a4.y}, o0 = {a0.x-a4.x, a0.y-a4.y};
      float2 e1 = {a2.x+a6.x, a2.y+a6.y}, o1 = {a2.x-a6.x, a2.y-a6.y};
      float2 e2 = {a1.x+a5.x, a1.y+a5.y}, o2 = {a1.x-a5.x, a1.y-a5.y};
      float2 e3 = {a3.x+a7.x, a3.y+a7.y}, o3 = {a3.x-a7.x, a3.y-a7.y};
      float2 E0 = {e0.x+e1.x, e0.y+e1.y}, E1 = {e0.x-e1.x, e0.y-e1.y};
      float2 E2 = {e2.x+e3.x, e2.y+e3.y}, E3 = {e2.x-e3.x, e2.y-e3.y};
      float2 u0 = {E0.x+E2.x, E0.y+E2.y};
      float2 u4 = {E0.x-E2.x, E0.y-E2.y};
      float2 njE3 = {E3.y, -E3.x};
      float2 u2 = {E1.x+njE3.x, E1.y+njE3.y};
      float2 u6 = {E1.x-njE3.x, E1.y-njE3.y};
      float2 W1o2 = {C*(o2.x+o2.y), C*(o2.y-o2.x)};
      float2 W3o2 = {C*(o2.y-o2.x), -C*(o2.x+o2.y)};
      float2 W1o3 = {C*(o3.x+o3.y), C*(o3.y-o3.x)};
      float2 W3o3 = {C*(o3.y-o3.x), -C*(o3.x+o3.y)};
      float2 njo1 = {o1.y, -o1.x};
      float2 u1 = {o0.x + W1o2.x + njo1.x + W3o3.x, o0.y + W1o2.y + njo1.y + W3o3.y};
      float2 u3 = {o0.x + W3o2.x - njo1.x + W1o3.x, o0.y + W3o2.y - njo1.y + W1o3.y};
      float2 u5 = {o0.x - W1o2.x + njo1.x - W3o3.x, o0.y - W1o2.y + njo1.y - W3o3.y};
      float2 u7 = {o0.x - W3o2.x - njo1.x - W1o3.x, o0.y - W3o2.y - njo1.y - W1o3.y};
      const float2 w1 = tw[j*step];
      const float2 w2 = tw[2*j*step];
      const float2 w4 = tw[4*j*step];
      const float2 w3 = cmul(w1, w2);
      const float2 w5 = cmul(w1, w4);
      const float2 w6 = cmul(w2, w4);
      const float2 w7 = cmul(w3, w4);
      Z[base]     = u0;
      Z[base+q]   = cmul(u1, w1);
      Z[base+2*q] = cmul(u2, w2);
      Z[base+3*q] = cmul(u3, w3);
      Z[base+4*q] = cmul(u4, w4);
      Z[base+5*q] = cmul(u5, w5);
      Z[base+6*q] = cmul(u6, w6);
      Z[base+7*q] = cmul(u7, w7);
    }
    __syncthreads();
  }
}

// ---------------- radix-8 DIT inverse FFT: digit-reversed input -> natural output ----------------
DEV void fft4096_dit8_inv(float2* Z, const float2* __restrict__ tw, int tid){
  const float C = 0.70710678118654752f;
  #pragma unroll
  for (int s = 1; s <= 4; ++s){
    const int q = 1 << (3*(s-1));
    const int step = 1 << (12 - 3*s);
    #pragma unroll
    for (int tt = tid; tt < 512; tt += 256){
      const int j = tt & (q-1);
      const int base = ((tt >> (3*(s-1))) << (3*s)) + j;
      float2 a0 = Z[base],       a1 = Z[base+q],   a2 = Z[base+2*q], a3 = Z[base+3*q];
      float2 a4 = Z[base+4*q],   a5 = Z[base+5*q], a6 = Z[base+6*q], a7 = Z[base+7*q];
      float2 w1 = tw[j*step];   w1.y = -w1.y;
      float2 w2 = tw[2*j*step]; w2.y = -w2.y;
      float2 w4 = tw[4*j*step]; w4.y = -w4.y;
      const float2 w3 = cmul(w1, w2);
      const float2 w5 = cmul(w1, w4);
      const float2 w6 = cmul(w2, w4);
      const float2 w7 = cmul(w3, w4);
      a1 = cmul(a1, w1); a2 = cmul(a2, w2); a3 = cmul(a3, w3);
      a4 = cmul(a4, w4); a5 = cmul(a5, w5); a6 = cmul(a6, w6); a7 = cmul(a7, w7);
      float2 e0 = {a0.x+a4.x, a0.y+a4.y}, o0 = {a0.x-a4.x, a0.y-a4.y};
      float2 e1 = {a2.x+a6.x, a2.y+a6.y}, o1 = {a2.x-a6.x, a2.y-a6.y};
      float2 e2 = {a1.x+a5.x, a1.y+a5.y}, o2 = {a1.x-a5.x, a1.y-a5.y};
      float2 e3 = {a3.x+a7.x, a3.y+a7.y}, o3 = {a3.x-a7.x, a3.y-a7.y};
      float2 E0 = {e0.x+e1.x, e0.y+e1.y}, E1 = {e0.x-e1.x, e0.y-e1.y};
      float2 E2 = {e2.x+e3.x, e2.y+e3.y}, E3 = {e2.x-e3.x, e2.y-e3.y};
      float2 pjE3 = {-E3.y, E3.x};
      float2 W1o2 = {C*(o2.x-o2.y), C*(o2.x+o2.y)};
      float2 W3o2 = {-C*(o2.x+o2.y), C*(o2.x-o2.y)};
      float2 W1o3 = {C*(o3.x-o3.y), C*(o3.x+o3.y)};
      float2 W3o3 = {-C*(o3.x+o3.y), C*(o3.x-o3.y)};
      float2 pjo1 = {-o1.y, o1.x};
      Z[base]     = make_float2(E0.x+E2.x, E0.y+E2.y);
      Z[base+q]   = make_float2(o0.x + W1o2.x + pjo1.x + W3o3.x, o0.y + W1o2.y + pjo1.y + W3o3.y);
      Z[base+2*q] = make_float2(E1.x+pjE3.x, E1.y+pjE3.y);
      Z[base+3*q] = make_float2(o0.x + W3o2.x - pjo1.x + W1o3.x, o0.y + W3o2.y - pjo1.y + W1o3.y);
      Z[base+4*q] = make_float2(E0.x-E2.x, E0.y-E2.y);
      Z[base+5*q] = make_float2(o0.x - W1o2.x + pjo1.x - W3o3.x, o0.y - W1o2.y + pjo1.y - W3o3.y);
      Z[base+6*q] = make_float2(E1.x-pjE3.x, E1.y-pjE3.y);
      Z[base+7*q] = make_float2(o0.x - W3o2.x - pjo1.x - W1o3.x, o0.y - W3o2.y - pjo1.y - W1o3.y);
    }
    __syncthreads();
  }
}

// ---------------- FFT of (q + i*k) per (b,h,d); write S slice (rev-domain), no atomics ----------------
__global__ __launch_bounds__(256) void k_fftcorr(const u16* __restrict__ Qt, const u16* __restrict__ Kt,
                                                 const float2* __restrict__ twg, float* __restrict__ S){
  __shared__ float2 Z[4096];      // 32 KB
  const int tid = threadIdx.x;
  const int bh = blockIdx.x, dg = blockIdx.y;
  float2 sa[16];
  #pragma unroll
  for (int j = 0; j < 16; ++j) sa[j] = make_float2(0.f, 0.f);
  for (int dd = 0; dd < 8; ++dd){
    const int d = dg*8 + dd;
    const u16* q  = Qt + ((size_t)bh*64 + d) * 4096;
    const u16* kp = Kt + ((size_t)bh*64 + d) * 4096;
    for (int i = tid; i < 4096; i += 256)
      Z[i] = make_float2(bf2f(q[i]), bf2f(kp[i]));
    __syncthreads();
    fft4096_dif8(Z, twg, tid);
    #pragma unroll
    for (int j = 0; j < 16; ++j){
      const int p = j*256 + tid;
      const int f = rev8(p);
      const int p2 = rev8((4096 - f) & 4095);
      const float2 a = Z[p];
      const float2 c = Z[p2];
      const float qr = 0.5f * (a.x + c.x);
      const float qi = 0.5f * (a.y - c.y);
      const float kr = 0.5f * (a.y + c.y);
      const float ki = 0.5f * (c.x - a.x);
      sa[j].x += qr*kr + qi*ki;     // Re(qf * conj(kf))
      sa[j].y += qi*kr - qr*ki;     // Im(qf * conj(kf))
    }
    __syncthreads();
  }
  float2* Sg = (float2*)S + ((size_t)dg*128 + bh) * 4096;
  #pragma unroll
  for (int j = 0; j < 16; ++j)
    Sg[j*256 + tid] = sa[j];
}

// ---------------- sum 8 S slices; inverse DIT FFT -> corr; softmax over L -> attn ----------------
__global__ __launch_bounds__(256) void k_isoftmax(const float* __restrict__ S, const float2* __restrict__ twg,
                                                  float* __restrict__ attn){
  __shared__ float2 Z[4096];
  __shared__ float red[4];
  __shared__ float bc;
  const int tid = threadIdx.x;
  const int bh = blockIdx.x;
  const float2* S2 = (const float2*)S;
  for (int i = tid; i < 4096; i += 256){
    float2 acc = make_float2(0.f, 0.f);
    #pragma unroll
    for (int g = 0; g < 8; ++g){
      const float2 v = S2[((size_t)g*128 + bh) * 4096 + i];
      acc.x += v.x; acc.y += v.y;
    }
    Z[i] = acc;
  }
  __syncthreads();
  fft4096_dit8_inv(Z, twg, tid);      // rev-domain in -> natural out (unnormalized)
  const float scale = 1.0f / (4096.0f * 64.0f);   // 1/N (ifft) * 1/HD (mean over d)
  float cr[16];
  float lmax = -1e30f;
  #pragma unroll
  for (int j = 0; j < 16; ++j){
    const float c = Z[j*256 + tid].x * scale;
    cr[j] = c;
    lmax = fmaxf(lmax, c);
  }
  #pragma unroll
  for (int o = 32; o > 0; o >>= 1) lmax = fmaxf(lmax, __shfl_down(lmax, o));
  if ((tid & 63) == 0) red[tid >> 6] = lmax;
  __syncthreads();
  if (tid == 0) bc = fmaxf(fmaxf(red[0], red[1]), fmaxf(red[2], red[3]));
  __syncthreads();
  const float gmax = bc;
  float lsum = 0.f;
  #pragma unroll
  for (int j = 0; j < 16; ++j){ cr[j] = __expf(cr[j] - gmax); lsum += cr[j]; }
  #pragma unroll
  for (int o = 32; o > 0; o >>= 1) lsum += __shfl_down(lsum, o);
  if ((tid & 63) == 0) red[tid >> 6] = lsum;
  __syncthreads();
  if (tid == 0) bc = red[0] + red[1] + red[2] + red[3];
  __syncthreads();
  const float inv = 1.0f / bc;
  float* at = attn + (size_t)bh * 4096;
  #pragma unroll
  for (int j = 0; j < 16; ++j) at[j*256 + tid] = cr[j] * inv;
}

// ---------------- yws[b][lq][h][:] = sum_{l in chunk} attn[b,h,l] * y[b,l,:]  (slice, no atomics) ----------------
__global__ __launch_bounds__(256) void k_yw(const float* __restrict__ attn, const u16* __restrict__ Y,
                                            float* __restrict__ yws){
  __shared__ float at[128*20 + 4];
  const int b = blockIdx.x, lq = blockIdx.y;
  const int l0 = lq * 128;
  const int tid = threadIdx.x;
  for (int idx = tid; idx < 2048; idx += 256){
    const int h = idx >> 7, l = idx & 127;
    at[l*20 + h] = attn[((size_t)b*16 + h)*4096 + l0 + l];
  }
  __syncthreads();
  float acc[16][4];
  #pragma unroll
  for (int h = 0; h < 16; ++h)
    #pragma unroll
    for (int j = 0; j < 4; ++j) acc[h][j] = 0.f;
  const u16* yb = Y + ((size_t)b*4096 + l0)*1024 + tid*4;
  for (int l = 0; l < 128; ++l){
    const ushort4 yv4 = *(const ushort4*)(yb + (size_t)l*1024);
    const float y0 = bf2f(yv4.x), y1 = bf2f(yv4.y), y2 = bf2f(yv4.z), y3 = bf2f(yv4.w);
    #pragma unroll
    for (int hq = 0; hq < 4; ++hq){
      const float4 a4 = *(const float4*)&at[l*20 + hq*4];
      acc[hq*4+0][0] += a4.x*y0; acc[hq*4+0][1] += a4.x*y1; acc[hq*4+0][2] += a4.x*y2; acc[hq*4+0][3] += a4.x*y3;
      acc[hq*4+1][0] += a4.y*y0; acc[hq*4+1][1] += a4.y*y1; acc[hq*4+1][2] += a4.y*y2; acc[hq*4+1][3] += a4.y*y3;
      acc[hq*4+2][0] += a4.z*y0; acc[hq*4+2][1] += a4.z*y1; acc[hq*4+2][2] += a4.z*y2; acc[hq*4+2][3] += a4.z*y3;
      acc[hq*4+3][0] += a4.w*y0; acc[hq*4+3][1] += a4.w*y1; acc[hq*4+3][2] += a4.w*y2; acc[hq*4+3][3] += a4.w*y3;
    }
  }
  float* ywb = yws + ((size_t)(b*32 + lq)*16) * 1024 + tid*4;
  #pragma unroll
  for (int h = 0; h < 16; ++h)
    #pragma unroll
    for (int j = 0; j < 4; ++j)
      ywb[(size_t)h*1024 + j] = acc[h][j];
}

// ---------------- oav[b, hd*16+h] = bv[h*64+hd] + (sum_lq yws[b][lq][h,:]) . Wv[h*64+hd,:] ----------------
__global__ __launch_bounds__(256) void k_vproj(const float* __restrict__ yws, const float* __restrict__ Wv,
                                               const float* __restrict__ bv, float* __restrict__ oav){
  __shared__ float yv[1024];
  const int b = blockIdx.x, h = blockIdx.y;
  const int tid = threadIdx.x;
  for (int i = tid; i < 1024; i += 256){
    float a = 0.f;
    #pragma unroll 8
    for (int g = 0; g < 32; ++g)
      a += yws[((size_t)(b*32 + g)*16 + h)*1024 + i];
    yv[i] = a;
  }
  __syncthreads();
  const int hd = tid >> 2, q = tid & 3;
  const float4* wr = (const float4*)(Wv + (size_t)(h*64 + hd)*1024 + q*256);
  float acc = 0.f;
  #pragma unroll 4
  for (int i = 0; i < 64; ++i){
    const float4 w4 = wr[i];
    acc += yv[q*256+4*i]*w4.x + yv[q*256+4*i+1]*w4.y + yv[q*256+4*i+2]*w4.z + yv[q*256+4*i+3]*w4.w;
  }
  acc += __shfl_xor(acc, 1);
  acc += __shfl_xor(acc, 2);
  if (q == 0) oav[(size_t)b*1024 + hd*16 + h] = acc + bv[h*64 + hd];
}

// ---------------- proj = oav @ Wo^T + bo  (8 x 1024) ----------------
__global__ __launch_bounds__(256) void k_proj(const float* __restrict__ oav, const float* __restrict__ Wo,
                                              const float* __restrict__ bo, float* __restrict__ proj){
  const int b = blockIdx.x;
  const int o = blockIdx.y * 256 + threadIdx.x;
  __shared__ float xin[1024];
  for (int i = threadIdx.x; i < 1024; i += 256) xin[i] = oav[(size_t)b*1024 + i];
  __syncthreads();
  float acc = bo[o];
  const float4* wr = (const float4*)(Wo + (size_t)o * 1024);
  #pragma unroll 4
  for (int i = 0; i < 256; ++i){
    const float4 w4 = wr[i];
    acc += xin[4*i]*w4.x + xin[4*i+1]*w4.y + xin[4*i+2]*w4.z + xin[4*i+3]*w4.w;
  }
  proj[(size_t)b*1024 + o] = acc;
}

// ---------------- fused decomp+LN2, barrier-free: wave owns one l-row, lane owns 16 d ----------------
// grid (8 b, 64 lc), 512 threads = 8 waves; wave w handles l = lc*64 + w*8 .. +7.
__global__ __launch_bounds__(512) void k_decln(const float* __restrict__ x, const float* __restrict__ proj,
                                               const float* __restrict__ w, const float* __restrict__ bvec,
                                               float* __restrict__ out, u16* __restrict__ y){
  const int b = blockIdx.x, lc = blockIdx.y;
  const int wave = threadIdx.x >> 6, lane = threadIdx.x & 63;
  const int l0 = lc*64 + wave*8;
  const int d0 = lane * 16;
  const float* xb = x + (size_t)b*4096*1024 + d0;
  float* ob = out + (size_t)b*4096*1024 + d0;
  u16* yb = y + (size_t)b*4096*1024 + d0;
  float pv[16], wv[16], bv[16], wsum[16];
  #pragma unroll
  for (int k = 0; k < 4; ++k){
    const float4 p4 = *(const float4*)(proj + (size_t)b*1024 + d0 + k*4);
    const float4 w4 = *(const float4*)(w + d0 + k*4);
    const float4 b4 = *(const float4*)(bvec + d0 + k*4);
    pv[k*4+0]=p4.x; pv[k*4+1]=p4.y; pv[k*4+2]=p4.z; pv[k*4+3]=p4.w;
    wv[k*4+0]=w4.x; wv[k*4+1]=w4.y; wv[k*4+2]=w4.z; wv[k*4+3]=w4.w;
    bv[k*4+0]=b4.x; bv[k*4+1]=b4.y; bv[k*4+2]=b4.z; bv[k*4+3]=b4.w;
    wsum[k*4+0]=0.f; wsum[k*4+1]=0.f; wsum[k*4+2]=0.f; wsum[k*4+3]=0.f;
  }
  float cnt = 0.f;
  const int lo = (l0 - 12 < 0) ? 0 : l0 - 12;
  const int hi = (l0 + 11 > 4095) ? 4095 : l0 + 11;
  for (int ll = lo; ll <= hi; ++ll){
    #pragma unroll
    for (int k = 0; k < 4; ++k){
      const float4 v = *(const float4*)(xb + (size_t)ll*1024 + k*4);
      wsum[k*4+0]+=v.x; wsum[k*4+1]+=v.y; wsum[k*4+2]+=v.z; wsum[k*4+3]+=v.w;
    }
    cnt += 1.f;
  }
  for (int l = l0; l < l0 + 8; ++l){
    if (l + 12 < 4096){
      #pragma unroll
      for (int k = 0; k < 4; ++k){
        const float4 v = *(const float4*)(xb + (size_t)(l+12)*1024 + k*4);
        wsum[k*4+0]+=v.x; wsum[k*4+1]+=v.y; wsum[k*4+2]+=v.z; wsum[k*4+3]+=v.w;
      }
      cnt += 1.f;
    }
    float x2[16];
    float s1 = 0.f, s2 = 0.f;
    #pragma unroll
    for (int k = 0; k < 4; ++k){
      const float4 v = *(const float4*)(xb + (size_t)l*1024 + k*4);
      const float xc[4] = {v.x, v.y, v.z, v.w};
      #pragma unroll
      for (int j = 0; j < 4; ++j){
        const int idx = k*4 + j;
        x2[idx] = xc[j] + pv[idx] - (wsum[idx] + cnt*pv[idx]) * 0.04f;
        s1 += x2[idx]; s2 += x2[idx]*x2[idx];
      }
      float4 o4 = {x2[k*4+0], x2[k*4+1], x2[k*4+2], x2[k*4+3]};
      *(float4*)(ob + (size_t)l*1024 + k*4) = o4;
    }
    #pragma unroll
    for (int o = 32; o > 0; o >>= 1){ s1 += __shfl_xor(s1, o); s2 += __shfl_xor(s2, o); }
    const float mu = s1 * (1.0f/1024.0f);
    const float rs = rsqrtf(s2*(1.0f/1024.0f) - mu*mu + 1e-6f);
    #pragma unroll
    for (int k = 0; k < 4; ++k){
      ushort4 y4;
      y4.x = f2bf((x2[k*4+0]-mu)*rs*wv[k*4+0] + bv[k*4+0]);
      y4.y = f2bf((x2[k*4+1]-mu)*rs*wv[k*4+1] + bv[k*4+1]);
      y4.z = f2bf((x2[k*4+2]-mu)*rs*wv[k*4+2] + bv[k*4+2]);
      y4.w = f2bf((x2[k*4+3]-mu)*rs*wv[k*4+3] + bv[k*4+3]);
      *(ushort4*)(yb + (size_t)l*1024 + k*4) = y4;
    }
    if (l >= 12){
      #pragma unroll
      for (int k = 0; k < 4; ++k){
        const float4 v = *(const float4*)(xb + (size_t)(l-12)*1024 + k*4);
        wsum[k*4+0]-=v.x; wsum[k*4+1]-=v.y; wsum[k*4+2]-=v.z; wsum[k*4+3]-=v.w;
      }
      cnt -= 1.f;
    }
  }
}

extern "C" void kernel_launch(void* const* d_in, const int* in_sizes, int n_in,
                              void* d_out, int out_size, void* d_ws, size_t ws_size,
                              hipStream_t stream){
  const float* x    = (const float*)d_in[0];
  const float* ln1w = (const float*)d_in[1];
  const float* ln1b = (const float*)d_in[2];
  const float* Wq   = (const float*)d_in[3];
  const float* bq   = (const float*)d_in[4];
  const float* Wk   = (const float*)d_in[5];
  const float* bk   = (const float*)d_in[6];
  const float* Wv   = (const float*)d_in[7];
  const float* bv   = (const float*)d_in[8];
  const float* Wo   = (const float*)d_in[9];
  const float* bo   = (const float*)d_in[10];
  const float* ln2w = (const float*)d_in[11];
  const float* ln2b = (const float*)d_in[12];
  const float* W1   = (const float*)d_in[13];
  const float* b1   = (const float*)d_in[14];
  const float* W2   = (const float*)d_in[15];
  const float* b2   = (const float*)d_in[16];
  float* out = (float*)d_out;

  char* ws = (char*)d_ws;
  // [0,32MB): S slices (fftcorr->isoftmax), then yws slices (yw->vproj), then H1 (MLP).
  float* S    = (float*)(ws + 0);             // 8 x 128 x 8192 f32 = 32MB
  float* yws  = (float*)(ws + 0);             // 8 x 32 x 16 x 1024 f32 = 16MB (after isoftmax)
  u16* Qt   = (u16*)(ws + 134217728);         // 64MB (B,H,64,L) bf16
  u16* Kt   = (u16*)(ws + 201326592);         // 64MB
  u16* H1   = (u16*)(ws + 0);                 // 256MB late (after vproj done with yws)
  u16* Y    = (u16*)(ws + 268435456);         // 64MB; ln1 y, later ln2 y
  float2* twg = (float2*)(ws + 339738624);    // 16 KB
  float* attn = (float*)(ws + 339755008);     // 2 MB
  float* oav  = (float*)(ws + 342376448);     // 32 KB
  float* proj = (float*)(ws + 342409216);     // 32 KB
  float* bqk  = (float*)(ws + 342441984);     // 8 KB
  u16* Wqkb   = (u16*)(ws + 342450176);       // 4 MB
  u16* W1b    = (u16*)(ws + 346644480);       // 8 MB
  u16* W2b    = (u16*)(ws + 355033088);       // 8 MB

  // fused LN1 + weight cvt + bias cat + twiddle (single launch; LN blocks first)
  k_prepln<<<73740, 256, 0, stream>>>(x, ln1w, ln1b, Y, Wq, Wk, W1, W2, bq, bk,
                                      Wqkb, W1b, W2b, bqk, twg);

  // fused QK projection with transposed store straight into Qt/Kt (MODE 3)
  k_gemm5<3><<<1024, 512, 0, stream>>>(Y, Wqkb, bqk, Qt, Kt, 32768, 2048, 1024);

  // S slices (rev-domain) = per-dg sum_d rfft(Q_d) * conj(rfft(K_d)); no atomics
  k_fftcorr<<<dim3(128, 8), 256, 0, stream>>>(Qt, Kt, twg, S);
  // corr = ifft(sum_g S_g)/(N*HD); attn = softmax(corr)
  k_isoftmax<<<128, 256, 0, stream>>>(S, twg, attn);

  // yws slices = per-lq sum_l attn*y;  oav = (sum yws) @ Wv^T + bv;  proj = oav @ Wo^T + bo
  k_yw<<<dim3(8, 32), 256, 0, stream>>>(attn, Y, yws);
  k_vproj<<<dim3(8, 16), 256, 0, stream>>>(yws, Wv, bv, oav);
  k_proj<<<dim3(8, 4), 256, 0, stream>>>(oav, Wo, bo, proj);

  // fused: x2 = (x + proj) - movavg25(x + proj) -> d_out;  Y = LN2(x2)   (barrier-free)
  k_decln<<<dim3(8, 64), 512, 0, stream>>>(x, proj, ln2w, ln2b, out, Y);

  // MLP
  k_gemm5<1><<<2048, 512, 0, stream>>>(Y, W1b, b1, H1, nullptr, 32768, 4096, 1024);
  k_gemm5<2><<<512, 512, 0, stream>>>(H1, W2b, b2, out, nullptr, 32768, 1024, 4096);
}